// Round 1
// baseline (7305.605 us; speedup 1.0000x reference)
//
#include <hip/hip_runtime.h>
#include <hip/hip_bf16.h>

// Problem constants (fixed by the reference)
constexpr int NUM_ENT = 100000;
constexpr int NUM_REL = 400;
constexpr int D_IN    = 200;
constexpr int D_OUT   = 400;
constexpr int N_EDGES = 600000;
constexpr int HALF_E  = N_EDGES / 2;
constexpr int BATCH   = 1024;
constexpr float BN_EPS = 1e-5f;

// All tensors f32 per the reference (prior rounds: bf16 I/O failed the
// harness contract, f32-in/f32-out passes).

// ---------------------------------------------------------------------------
// K0: build W600 = [in_w ; out_w ; Lw] (600 x 400), where
// Lw[j][c] = sum_k loop_rel[(j+k)%200] * loop_w[k][c]
// ---------------------------------------------------------------------------
__global__ void build_w600(const float* __restrict__ in_w,
                           const float* __restrict__ out_w,
                           const float* __restrict__ loop_w,
                           const float* __restrict__ loop_rel,
                           float* __restrict__ W600) {
    int idx = blockIdx.x * blockDim.x + threadIdx.x;
    if (idx >= 600 * D_OUT) return;
    int k = idx / D_OUT, c = idx % D_OUT;
    float v;
    if (k < 200) {
        v = in_w[k * D_OUT + c];
    } else if (k < 400) {
        v = out_w[(k - 200) * D_OUT + c];
    } else {
        int j = k - 400;
        float acc = 0.f;
        for (int kk = 0; kk < D_IN; ++kk) {
            int idx2 = j + kk;
            if (idx2 >= D_IN) idx2 -= D_IN;
            acc += loop_rel[idx2] * loop_w[kk * D_OUT + c];
        }
        v = acc;
    }
    W600[idx] = v;
}

// ---------------------------------------------------------------------------
// K1 (REWRITTEN): per-edge ccorr + scatter into P (NUM_ENT x 400).
//   One edge per 64-thread block. Lanes 0..49 each produce 4 consecutive
//   output columns (k0 = 4*lane). b staged duplicated in LDS (no modulo);
//   j unrolled by 8 with a 12-float sliding b-window in registers:
//   per 8-j step: 2 broadcast b128 (a) + 3 per-lane b128 (b) vs 32 FMAs
//   -> VALU-bound instead of 3x LDS-bound.
//   ccorr(a,b)[k] = sum_j a[j] * b[(j+k) % 200]
// ---------------------------------------------------------------------------
__global__ __launch_bounds__(64) void edge_kernel(
        const float* __restrict__ ent, const float* __restrict__ rel,
        const int* __restrict__ src, const int* __restrict__ dst,
        const int* __restrict__ etype, const float* __restrict__ norm,
        float* __restrict__ P) {
    __shared__ __align__(16) float a_s[D_IN];        // 200
    __shared__ __align__(16) float b_s[2 * D_IN];    // 400 (duplicated)
    const int e    = blockIdx.x;
    const int lane = threadIdx.x;
    const int s  = src[e];
    const int ty = etype[e];

    // stage a: 200 floats = 50 float4, lanes 0..49
    if (lane < 50) {
        *reinterpret_cast<float4*>(&a_s[lane * 4]) =
            *reinterpret_cast<const float4*>(&ent[(size_t)s * D_IN + lane * 4]);
    }
    // stage b duplicated: 400 floats = 100 float4 -> lanes do t4 = lane, lane+64
    for (int t4 = lane; t4 < 100; t4 += 64) {
        int o = 4 * t4;
        if (o >= D_IN) o -= D_IN;
        *reinterpret_cast<float4*>(&b_s[4 * t4]) =
            *reinterpret_cast<const float4*>(&rel[(size_t)ty * D_IN + o]);
    }
    __syncthreads();

    if (lane < 50) {
        const int k0 = lane * 4;
        float acc0 = 0.f, acc1 = 0.f, acc2 = 0.f, acc3 = 0.f;
        for (int j = 0; j < D_IN; j += 8) {
            float4 aA = *reinterpret_cast<const float4*>(&a_s[j]);
            float4 aB = *reinterpret_cast<const float4*>(&a_s[j + 4]);
            float4 b0 = *reinterpret_cast<const float4*>(&b_s[j + k0]);
            float4 b1 = *reinterpret_cast<const float4*>(&b_s[j + k0 + 4]);
            float4 b2 = *reinterpret_cast<const float4*>(&b_s[j + k0 + 8]);
            const float aw[8]  = {aA.x, aA.y, aA.z, aA.w,
                                  aB.x, aB.y, aB.z, aB.w};
            const float bw[12] = {b0.x, b0.y, b0.z, b0.w,
                                  b1.x, b1.y, b1.z, b1.w,
                                  b2.x, b2.y, b2.z, b2.w};
            #pragma unroll
            for (int m = 0; m < 8; ++m) {
                acc0 += aw[m] * bw[m + 0];
                acc1 += aw[m] * bw[m + 1];
                acc2 += aw[m] * bw[m + 2];
                acc3 += aw[m] * bw[m + 3];
            }
        }
        const float nv = norm[e];
        float* outp = P + (size_t)dst[e] * 400 + ((e < HALF_E) ? 0 : 200) + k0;
        atomicAdd(outp + 0, nv * acc0);
        atomicAdd(outp + 1, nv * acc1);
        atomicAdd(outp + 2, nv * acc2);
        atomicAdd(outp + 3, nv * acc3);
    }
}

// ---------------------------------------------------------------------------
// K2: x = A @ W600 / 3 + bias, A = [P | ent] (K=600). Only emits column
// sum / sumsq (BN statistics) — x itself is never stored.
// Tile 64 rows x 64 cols, K-chunk 40. grid = (1563, 7).
// ---------------------------------------------------------------------------
__global__ __launch_bounds__(256) void x_gemm_stats(
        const float* __restrict__ P, const float* __restrict__ ent,
        const float* __restrict__ W, const float* __restrict__ bias,
        float* __restrict__ sum_g, float* __restrict__ ssq_g) {
    __shared__ __align__(16) float As[40][64];
    __shared__ __align__(16) float Bs[40][64];
    __shared__ float lsum[64], lssq[64];
    int tid = threadIdx.x;
    int row0 = blockIdx.x * 64;
    int col0 = blockIdx.y * 64;
    int tx = tid & 15, ty = tid >> 4;
    float acc[4][4] = {};
    for (int kc = 0; kc < 600; kc += 40) {
        #pragma unroll
        for (int i = 0; i < 10; ++i) {
            int e = tid + 256 * i;           // 0..2559 = 64 rows x 40 k
            int rr = e / 40, kk = e % 40;
            int row = row0 + rr, k = kc + kk;
            float v = 0.f;
            if (row < NUM_ENT)
                v = (k < 400) ? P[(size_t)row * 400 + k]
                              : ent[(size_t)row * D_IN + (k - 400)];
            As[kk][rr] = v;
        }
        #pragma unroll
        for (int i = 0; i < 10; ++i) {
            int e = tid + 256 * i;           // 40 k x 64 c
            int kk = e / 64, cc = e % 64;
            int c = col0 + cc;
            Bs[kk][cc] = (c < D_OUT) ? W[(size_t)(kc + kk) * D_OUT + c] : 0.f;
        }
        __syncthreads();
        #pragma unroll
        for (int kk = 0; kk < 40; ++kk) {
            float4 a4 = *reinterpret_cast<const float4*>(&As[kk][tx << 2]);
            float4 b4 = *reinterpret_cast<const float4*>(&Bs[kk][ty << 2]);
            const float av[4] = {a4.x, a4.y, a4.z, a4.w};
            const float bv[4] = {b4.x, b4.y, b4.z, b4.w};
            #pragma unroll
            for (int i = 0; i < 4; ++i)
                #pragma unroll
                for (int j = 0; j < 4; ++j)
                    acc[i][j] += av[i] * bv[j];
        }
        __syncthreads();
    }
    if (tid < 64) { lsum[tid] = 0.f; lssq[tid] = 0.f; }
    __syncthreads();
    #pragma unroll
    for (int j = 0; j < 4; ++j) {
        int c = col0 + (ty << 2) + j;
        if (c < D_OUT) {
            float bv = bias[c];
            float s = 0.f, q = 0.f;
            #pragma unroll
            for (int i = 0; i < 4; ++i) {
                int row = row0 + (tx << 2) + i;
                if (row < NUM_ENT) {
                    float xv = acc[i][j] * (1.f / 3.f) + bv;
                    s += xv;
                    q += xv * xv;
                }
            }
            atomicAdd(&lsum[(ty << 2) + j], s);
            atomicAdd(&lssq[(ty << 2) + j], q);
        }
    }
    __syncthreads();
    if (tid < 64) {
        int c = col0 + tid;
        if (c < D_OUT) {
            atomicAdd(&sum_g[c], lsum[tid]);
            atomicAdd(&ssq_g[c], lssq[tid]);
        }
    }
}

// ---------------------------------------------------------------------------
// K3: finalize BN: scale = gamma * rsqrt(var+eps), shift = beta - mean*scale
// ---------------------------------------------------------------------------
__global__ void bn_finalize(const float* __restrict__ sum_g,
                            const float* __restrict__ ssq_g,
                            const float* __restrict__ gamma,
                            const float* __restrict__ beta,
                            float* __restrict__ scale,
                            float* __restrict__ shift) {
    int c = blockIdx.x * blockDim.x + threadIdx.x;
    if (c < D_OUT) {
        float m = sum_g[c] * (1.f / (float)NUM_ENT);
        float v = ssq_g[c] * (1.f / (float)NUM_ENT) - m * m;
        float rs = rsqrtf(v + BN_EPS);
        float sc = gamma[c] * rs;
        scale[c] = sc;
        shift[c] = beta[c] - m * sc;
    }
}

// ---------------------------------------------------------------------------
// K4: R = rel_emb @ w_rel  (400 x 400)
// ---------------------------------------------------------------------------
__global__ void rel_gemm(const float* __restrict__ rel,
                         const float* __restrict__ w_rel,
                         float* __restrict__ R) {
    int idx = blockIdx.x * blockDim.x + threadIdx.x;
    if (idx >= NUM_REL * D_OUT) return;
    int i = idx / D_OUT, c = idx % D_OUT;
    float acc = 0.f;
    for (int k = 0; k < D_IN; ++k)
        acc += rel[(size_t)i * D_IN + k] * w_rel[(size_t)k * D_OUT + c];
    R[idx] = acc;
}

// ---------------------------------------------------------------------------
// K5: recompute x for the 1024 gathered head rows, apply BN+tanh, times
// rela row -> OBJ (1024 x 400)
// ---------------------------------------------------------------------------
__global__ __launch_bounds__(256) void obj_kernel(
        const float* __restrict__ P, const float* __restrict__ ent,
        const float* __restrict__ W, const float* __restrict__ bias,
        const float* __restrict__ scale, const float* __restrict__ shift,
        const float* __restrict__ R, const int* __restrict__ triples,
        float* __restrict__ OBJ) {
    __shared__ float As[600];
    int t = blockIdx.x;
    int h  = triples[t * 3 + 0];
    int rr = triples[t * 3 + 1];
    int tid = threadIdx.x;
    for (int k = tid; k < 600; k += 256)
        As[k] = (k < 400) ? P[(size_t)h * 400 + k]
                          : ent[(size_t)h * D_IN + (k - 400)];
    __syncthreads();
    for (int c = tid; c < D_OUT; c += 256) {
        float acc = 0.f;
        for (int k = 0; k < 600; ++k)
            acc += As[k] * W[(size_t)k * D_OUT + c];
        float xv = acc * (1.f / 3.f) + bias[c];
        float nv = tanhf(xv * scale[c] + shift[c]);
        OBJ[(size_t)t * D_OUT + c] = nv * R[(size_t)rr * D_OUT + c];
    }
}

// ---------------------------------------------------------------------------
// K6: score = sigmoid(OBJ @ emb_ent_w^T + ent_bias), out f32 (1024 x 100000)
// Tile 64 ents x 64 batch, K-chunk 40. grid = (1563, 16).
// ---------------------------------------------------------------------------
__global__ __launch_bounds__(256) void score_gemm(
        const float* __restrict__ emb, const float* __restrict__ OBJ,
        const float* __restrict__ ent_bias, float* __restrict__ out) {
    __shared__ __align__(16) float As[40][64];   // [k][n]  from emb_ent_w
    __shared__ __align__(16) float Bs[40][64];   // [k][t]  from OBJ
    int tid = threadIdx.x;
    int n0 = blockIdx.x * 64;
    int t0 = blockIdx.y * 64;
    int tx = tid & 15, ty = tid >> 4;
    float acc[4][4] = {};
    for (int kc = 0; kc < D_OUT; kc += 40) {
        #pragma unroll
        for (int i = 0; i < 10; ++i) {
            int e = tid + 256 * i;
            int rr = e / 40, kk = e % 40;
            int row = n0 + rr;
            As[kk][rr] = (row < NUM_ENT)
                       ? emb[(size_t)row * D_OUT + kc + kk] : 0.f;
        }
        #pragma unroll
        for (int i = 0; i < 10; ++i) {
            int e = tid + 256 * i;
            int tt = e / 40, kk = e % 40;
            Bs[kk][tt] = OBJ[(size_t)(t0 + tt) * D_OUT + kc + kk];
        }
        __syncthreads();
        #pragma unroll
        for (int kk = 0; kk < 40; ++kk) {
            float4 a4 = *reinterpret_cast<const float4*>(&As[kk][tx << 2]);
            float4 b4 = *reinterpret_cast<const float4*>(&Bs[kk][ty << 2]);
            const float av[4] = {a4.x, a4.y, a4.z, a4.w};
            const float bv[4] = {b4.x, b4.y, b4.z, b4.w};
            #pragma unroll
            for (int i = 0; i < 4; ++i)
                #pragma unroll
                for (int j = 0; j < 4; ++j)
                    acc[i][j] += av[i] * bv[j];
        }
        __syncthreads();
    }
    int n_base = n0 + (tx << 2);
    if (n_base < NUM_ENT) {   // NUM_ENT % 4 == 0, so full 4-run is valid
        #pragma unroll
        for (int j = 0; j < 4; ++j) {
            int t = t0 + (ty << 2) + j;
            float4 pk;
            float r[4];
            #pragma unroll
            for (int i = 0; i < 4; ++i) {
                float logit = acc[i][j] + ent_bias[n_base + i];
                r[i] = 1.f / (1.f + __expf(-logit));
            }
            pk.x = r[0]; pk.y = r[1]; pk.z = r[2]; pk.w = r[3];
            *reinterpret_cast<float4*>(&out[(size_t)t * NUM_ENT + n_base]) = pk;
        }
    }
}

// ---------------------------------------------------------------------------
extern "C" void kernel_launch(void* const* d_in, const int* in_sizes, int n_in,
                              void* d_out, int out_size, void* d_ws, size_t ws_size,
                              hipStream_t stream) {
    const float* ent      = (const float*)d_in[0];
    const float* rel      = (const float*)d_in[1];
    const float* in_w     = (const float*)d_in[2];
    const float* out_w    = (const float*)d_in[3];
    const float* loop_w   = (const float*)d_in[4];
    const float* w_rel    = (const float*)d_in[5];
    const float* loop_rel = (const float*)d_in[6];
    const float* bias_w   = (const float*)d_in[7];
    const float* gamma    = (const float*)d_in[8];
    const float* beta     = (const float*)d_in[9];
    const float* emb      = (const float*)d_in[10];
    const float* ent_bias = (const float*)d_in[11];
    const int*   src      = (const int*)d_in[12];
    const int*   dst      = (const int*)d_in[13];
    const int*   etype    = (const int*)d_in[14];
    const float* norm     = (const float*)d_in[15];
    const int*   triples  = (const int*)d_in[16];
    float* out            = (float*)d_out;

    float* ws_f  = (float*)d_ws;
    float* P     = ws_f;                       // 100000*400 = 40,000,000 f (160 MB)
    float* W600  = P + (size_t)NUM_ENT * 400;  // 600*400
    float* Rmat  = W600 + 600 * D_OUT;         // 400*400
    float* OBJ   = Rmat + NUM_REL * D_OUT;     // 1024*400
    float* SUM   = OBJ + (size_t)BATCH * D_OUT;
    float* SSQ   = SUM + D_OUT;
    float* SCALE = SSQ + D_OUT;
    float* SHIFT = SCALE + D_OUT;

    hipMemsetAsync(P, 0, (size_t)NUM_ENT * 400 * sizeof(float), stream);
    hipMemsetAsync(SUM, 0, 2 * D_OUT * sizeof(float), stream);

    build_w600<<<(600 * D_OUT + 255) / 256, 256, 0, stream>>>(
        in_w, out_w, loop_w, loop_rel, W600);

    edge_kernel<<<N_EDGES, 64, 0, stream>>>(ent, rel, src, dst, etype, norm, P);

    dim3 gx((NUM_ENT + 63) / 64, (D_OUT + 63) / 64);
    x_gemm_stats<<<gx, 256, 0, stream>>>(P, ent, W600, bias_w, SUM, SSQ);

    bn_finalize<<<2, 256, 0, stream>>>(SUM, SSQ, gamma, beta, SCALE, SHIFT);

    rel_gemm<<<(NUM_REL * D_OUT + 255) / 256, 256, 0, stream>>>(rel, w_rel, Rmat);

    obj_kernel<<<BATCH, 256, 0, stream>>>(P, ent, W600, bias_w, SCALE, SHIFT,
                                          Rmat, triples, OBJ);

    dim3 gs((NUM_ENT + 63) / 64, BATCH / 64);
    score_gemm<<<gs, 256, 0, stream>>>(emb, OBJ, ent_bias, out);
}